// Round 1
// baseline (5646.851 us; speedup 1.0000x reference)
//
#include <hip/hip_runtime.h>

// ---------------------------------------------------------------------------
// GNNEncoder: 4x SAGEConv + linear.
//   out = mean_{j in N(i)} h_j @ Wl + bl + h_i @ Wr   (relu on layers 1-3)
// Trick: mean_j(h_j) @ Wl == mean_j(h_j @ Wl)  -> transform FIRST, then
// aggregate in 64 dims (halves layer-1a edge traffic vs aggregating 128 dims).
// Round 0: atomic scatter-add aggregation (simple, correct). cnt computed once.
// ---------------------------------------------------------------------------

__global__ void count_kernel(const int* __restrict__ dst, int* __restrict__ cnt, int E) {
    int e = blockIdx.x * blockDim.x + threadIdx.x;
    if (e < E) atomicAdd(&cnt[dst[e]], 1);
}

__global__ void inv_kernel(const int* __restrict__ cnt, float* __restrict__ inv, int N) {
    int i = blockIdx.x * blockDim.x + threadIdx.x;
    if (i < N) {
        int c = cnt[i];
        inv[i] = 1.0f / (float)(c > 0 ? c : 1);
    }
}

// one edge handled by 16 threads; each does a float4 gather + 4 f32 atomics
__global__ __launch_bounds__(256) void scatter_kernel(
    const float* __restrict__ t, const int* __restrict__ src,
    const int* __restrict__ dst, float* __restrict__ s, int E)
{
    int tid = blockIdx.x * blockDim.x + threadIdx.x;
    int e = tid >> 4;
    if (e >= E) return;
    int part = tid & 15;
    int sn = src[e], dn = dst[e];
    const float4 v = *(const float4*)(t + (size_t)sn * 64 + part * 4);
    float* p = s + (size_t)dn * 64 + part * 4;
    atomicAdd(p + 0, v.x);
    atomicAdd(p + 1, v.y);
    atomicAdd(p + 2, v.z);
    atomicAdd(p + 3, v.w);
}

// C[M,DOUT] = A[M,K] @ W[K,DOUT]  (+ S*inv) (+ bias) (relu)
// block = 256 threads, 64 rows x DOUT cols per block, 4 x CT register tile.
template<int K, int DOUT, bool AGG, bool BIAS, bool RELU>
__global__ __launch_bounds__(256) void mm_kernel(
    const float* __restrict__ A, const float* __restrict__ W,
    const float* __restrict__ S, const float* __restrict__ invc,
    const float* __restrict__ bias, float* __restrict__ C, int M)
{
    constexpr int CT = DOUT / 16;             // 4 (DOUT=64) or 2 (DOUT=32)
    __shared__ float As[64][K + 4];           // +4 pad: keeps 16B align, breaks bank stride
    __shared__ float Ws[K * DOUT];
    const int tid  = threadIdx.x;
    const int row0 = blockIdx.x * 64;

    for (int i = tid * 4; i < K * DOUT; i += 1024) {
        *(float4*)&Ws[i] = *(const float4*)&W[i];
    }
    for (int i = tid * 4; i < 64 * K; i += 1024) {
        int r = i / K, c = i % K;
        int gr = row0 + r;
        float4 v = make_float4(0.f, 0.f, 0.f, 0.f);
        if (gr < M) v = *(const float4*)&A[(size_t)gr * K + c];
        *(float4*)&As[r][c] = v;
    }
    __syncthreads();

    const int tx = tid & 15, ty = tid >> 4;
    float acc[4][CT];
    #pragma unroll
    for (int r = 0; r < 4; ++r)
        #pragma unroll
        for (int c = 0; c < CT; ++c) acc[r][c] = 0.f;

    #pragma unroll 4
    for (int kk = 0; kk < K; ++kk) {
        float a[4];
        #pragma unroll
        for (int r = 0; r < 4; ++r) a[r] = As[ty * 4 + r][kk];
        float b[CT];
        #pragma unroll
        for (int c = 0; c < CT; ++c) b[c] = Ws[kk * DOUT + tx * CT + c];
        #pragma unroll
        for (int r = 0; r < 4; ++r)
            #pragma unroll
            for (int c = 0; c < CT; ++c)
                acc[r][c] += a[r] * b[c];
    }

    #pragma unroll
    for (int r = 0; r < 4; ++r) {
        int gr = row0 + ty * 4 + r;
        if (gr >= M) continue;
        float vinv = AGG ? invc[gr] : 0.f;
        float o[CT];
        #pragma unroll
        for (int c = 0; c < CT; ++c) {
            int col = tx * CT + c;
            float v = acc[r][c];
            if (AGG)  v += S[(size_t)gr * DOUT + col] * vinv;
            if (BIAS) v += bias[col];
            if (RELU) v = fmaxf(v, 0.f);
            o[c] = v;
        }
        if (CT == 4) {
            *(float4*)&C[(size_t)gr * DOUT + tx * 4] = make_float4(o[0], o[1], o[2], o[3]);
        } else {
            *(float2*)&C[(size_t)gr * DOUT + tx * 2] = make_float2(o[0], o[1]);
        }
    }
}

extern "C" void kernel_launch(void* const* d_in, const int* in_sizes, int n_in,
                              void* d_out, int out_size, void* d_ws, size_t ws_size,
                              hipStream_t stream) {
    const float* x     = (const float*)d_in[0];
    const int*   ei    = (const int*)  d_in[1];
    const float* W1a_l = (const float*)d_in[2];
    const float* b1a   = (const float*)d_in[3];
    const float* W1a_r = (const float*)d_in[4];
    const float* W1b_l = (const float*)d_in[5];
    const float* b1b   = (const float*)d_in[6];
    const float* W1b_r = (const float*)d_in[7];
    const float* W2a_l = (const float*)d_in[8];
    const float* b2a   = (const float*)d_in[9];
    const float* W2a_r = (const float*)d_in[10];
    const float* W2b_l = (const float*)d_in[11];
    const float* b2b   = (const float*)d_in[12];
    const float* W2b_r = (const float*)d_in[13];
    const float* Wlin  = (const float*)d_in[14];
    const float* blin  = (const float*)d_in[15];

    const int N = in_sizes[0] / 128;
    const int E = in_sizes[1] / 2;
    const int* src = ei;
    const int* dst = ei + E;

    // workspace layout (256B-aligned slices)
    size_t o = 0;
    auto take = [&](size_t bytes) -> void* {
        void* p = (char*)d_ws + o;
        o += (bytes + 255) & ~(size_t)255;
        return p;
    };
    int*   cnt = (int*)  take((size_t)N * 4);
    float* inv = (float*)take((size_t)N * 4);
    float* t   = (float*)take((size_t)N * 64 * 4);
    float* s   = (float*)take((size_t)N * 64 * 4);
    float* hA  = (float*)take((size_t)N * 64 * 4);
    float* hB  = (float*)take((size_t)N * 64 * 4);
    (void)ws_size; (void)n_in; (void)out_size;

    const int    mb  = (N + 63) / 64;
    const size_t sg  = ((size_t)E * 16 + 255) / 256;  // scatter grid
    const size_t sb  = (size_t)N * 64 * 4;            // s bytes

    // degree counts (graph-only, once)
    hipMemsetAsync(cnt, 0, (size_t)N * 4, stream);
    count_kernel<<<(E + 255) / 256, 256, 0, stream>>>(dst, cnt, E);
    inv_kernel<<<(N + 255) / 256, 256, 0, stream>>>(cnt, inv, N);

    // ---- layer 1a: x[*,128] -> hA[*,64], relu ----
    mm_kernel<128, 64, false, false, false><<<mb, 256, 0, stream>>>(x, W1a_l, nullptr, nullptr, nullptr, t, N);
    hipMemsetAsync(s, 0, sb, stream);
    scatter_kernel<<<sg, 256, 0, stream>>>(t, src, dst, s, E);
    mm_kernel<128, 64, true, true, true><<<mb, 256, 0, stream>>>(x, W1a_r, s, inv, b1a, hA, N);

    // ---- layer 1b: hA -> hB, relu ----
    mm_kernel<64, 64, false, false, false><<<mb, 256, 0, stream>>>(hA, W1b_l, nullptr, nullptr, nullptr, t, N);
    hipMemsetAsync(s, 0, sb, stream);
    scatter_kernel<<<sg, 256, 0, stream>>>(t, src, dst, s, E);
    mm_kernel<64, 64, true, true, true><<<mb, 256, 0, stream>>>(hA, W1b_r, s, inv, b1b, hB, N);

    // ---- layer 2a: hB -> hA, relu ----
    mm_kernel<64, 64, false, false, false><<<mb, 256, 0, stream>>>(hB, W2a_l, nullptr, nullptr, nullptr, t, N);
    hipMemsetAsync(s, 0, sb, stream);
    scatter_kernel<<<sg, 256, 0, stream>>>(t, src, dst, s, E);
    mm_kernel<64, 64, true, true, true><<<mb, 256, 0, stream>>>(hB, W2a_r, s, inv, b2a, hA, N);

    // ---- layer 2b: hA -> hB, NO relu ----
    mm_kernel<64, 64, false, false, false><<<mb, 256, 0, stream>>>(hA, W2b_l, nullptr, nullptr, nullptr, t, N);
    hipMemsetAsync(s, 0, sb, stream);
    scatter_kernel<<<sg, 256, 0, stream>>>(t, src, dst, s, E);
    mm_kernel<64, 64, true, true, false><<<mb, 256, 0, stream>>>(hA, W2b_r, s, inv, b2b, hB, N);

    // ---- final linear: hB[*,64] -> out[*,32] ----
    mm_kernel<64, 32, false, true, false><<<mb, 256, 0, stream>>>(hB, Wlin, nullptr, nullptr, blin, (float*)d_out, N);
}

// Round 2
// 656.763 us; speedup vs baseline: 8.5980x; 8.5980x over previous
//
#include <hip/hip_runtime.h>

// ---------------------------------------------------------------------------
// GNNEncoder: 4x SAGEConv + linear.
// R1: CSR pull-based aggregation (no f32 atomics). Per call:
//   count -> block scan (row_ptr, cursor) -> fill adj -> 4x [mm, gather, mm]
// Transform-first trick kept: mean_j(h_j) @ Wl == mean_j(h_j @ Wl).
// gather writes the MEAN directly (inv folded in); mm AGG path just adds S.
// ---------------------------------------------------------------------------

__global__ void count_kernel(const int* __restrict__ dst, int* __restrict__ cnt, int E) {
    int e = blockIdx.x * blockDim.x + threadIdx.x;
    if (e < E) atomicAdd(&cnt[dst[e]], 1);
}

__global__ void inv_kernel(const int* __restrict__ cnt, float* __restrict__ inv, int N) {
    int i = blockIdx.x * blockDim.x + threadIdx.x;
    if (i < N) {
        int c = cnt[i];
        inv[i] = 1.0f / (float)(c > 0 ? c : 1);
    }
}

// single block, 1024 threads: exclusive scan of cnt -> row_ptr[0..N], cursor copy
__global__ __launch_bounds__(1024) void scan_kernel(
    const int* __restrict__ cnt, int* __restrict__ row_ptr,
    int* __restrict__ cursor, int N)
{
    __shared__ int sums[1024];
    const int t = threadIdx.x;
    const int chunk = (N + 1023) >> 10;
    const int lo = t * chunk;
    const int hi = min(lo + chunk, N);
    int s = 0;
    for (int i = lo; i < hi; ++i) s += cnt[i];
    sums[t] = s;
    __syncthreads();
    // Hillis-Steele inclusive scan
    for (int off = 1; off < 1024; off <<= 1) {
        int v = (t >= off) ? sums[t - off] : 0;
        __syncthreads();
        sums[t] += v;
        __syncthreads();
    }
    int base = (t == 0) ? 0 : sums[t - 1];
    for (int i = lo; i < hi; ++i) {
        int c = cnt[i];
        row_ptr[i] = base;
        cursor[i]  = base;
        base += c;
    }
    if (t == 0) row_ptr[N] = sums[1023];
}

__global__ void fill_kernel(const int* __restrict__ src, const int* __restrict__ dst,
                            int* __restrict__ cursor, int* __restrict__ adj, int E)
{
    int e = blockIdx.x * blockDim.x + threadIdx.x;
    if (e < E) {
        int pos = atomicAdd(&cursor[dst[e]], 1);
        adj[pos] = src[e];
    }
}

// pull aggregation: one wave per node, lane = dim (64 dims). s[i] = mean_j t[j]
__global__ __launch_bounds__(256) void gather_kernel(
    const float* __restrict__ t, const int* __restrict__ adj,
    const int* __restrict__ row_ptr, const float* __restrict__ inv,
    float* __restrict__ s, int N)
{
    const int node = (blockIdx.x * 256 + threadIdx.x) >> 6;
    const int lane = threadIdx.x & 63;
    if (node >= N) return;
    const int beg = row_ptr[node], end = row_ptr[node + 1];
    float acc = 0.f;
    int j = beg;
    for (; j + 4 <= end; j += 4) {
        int n0 = adj[j], n1 = adj[j + 1], n2 = adj[j + 2], n3 = adj[j + 3];
        float v0 = t[(size_t)n0 * 64 + lane];
        float v1 = t[(size_t)n1 * 64 + lane];
        float v2 = t[(size_t)n2 * 64 + lane];
        float v3 = t[(size_t)n3 * 64 + lane];
        acc += (v0 + v1) + (v2 + v3);
    }
    for (; j < end; ++j) acc += t[(size_t)adj[j] * 64 + lane];
    s[(size_t)node * 64 + lane] = acc * inv[node];
}

// C[M,DOUT] = A[M,K] @ W[K,DOUT]  (+ S) (+ bias) (relu)
// block = 256 threads, 64 rows x DOUT cols per block, 4 x CT register tile.
template<int K, int DOUT, bool AGG, bool BIAS, bool RELU>
__global__ __launch_bounds__(256) void mm_kernel(
    const float* __restrict__ A, const float* __restrict__ W,
    const float* __restrict__ S, const float* __restrict__ bias,
    float* __restrict__ C, int M)
{
    constexpr int CT = DOUT / 16;             // 4 (DOUT=64) or 2 (DOUT=32)
    __shared__ float As[64][K + 4];
    __shared__ float Ws[K * DOUT];
    const int tid  = threadIdx.x;
    const int row0 = blockIdx.x * 64;

    for (int i = tid * 4; i < K * DOUT; i += 1024) {
        *(float4*)&Ws[i] = *(const float4*)&W[i];
    }
    for (int i = tid * 4; i < 64 * K; i += 1024) {
        int r = i / K, c = i % K;
        int gr = row0 + r;
        float4 v = make_float4(0.f, 0.f, 0.f, 0.f);
        if (gr < M) v = *(const float4*)&A[(size_t)gr * K + c];
        *(float4*)&As[r][c] = v;
    }
    __syncthreads();

    const int tx = tid & 15, ty = tid >> 4;
    float acc[4][CT];
    #pragma unroll
    for (int r = 0; r < 4; ++r)
        #pragma unroll
        for (int c = 0; c < CT; ++c) acc[r][c] = 0.f;

    #pragma unroll 4
    for (int kk = 0; kk < K; ++kk) {
        float a[4];
        #pragma unroll
        for (int r = 0; r < 4; ++r) a[r] = As[ty * 4 + r][kk];
        float b[CT];
        #pragma unroll
        for (int c = 0; c < CT; ++c) b[c] = Ws[kk * DOUT + tx * CT + c];
        #pragma unroll
        for (int r = 0; r < 4; ++r)
            #pragma unroll
            for (int c = 0; c < CT; ++c)
                acc[r][c] += a[r] * b[c];
    }

    #pragma unroll
    for (int r = 0; r < 4; ++r) {
        int gr = row0 + ty * 4 + r;
        if (gr >= M) continue;
        float o[CT];
        #pragma unroll
        for (int c = 0; c < CT; ++c) {
            int col = tx * CT + c;
            float v = acc[r][c];
            if (AGG)  v += S[(size_t)gr * DOUT + col];
            if (BIAS) v += bias[col];
            if (RELU) v = fmaxf(v, 0.f);
            o[c] = v;
        }
        if (CT == 4) {
            *(float4*)&C[(size_t)gr * DOUT + tx * 4] = make_float4(o[0], o[1], o[2], o[3]);
        } else {
            *(float2*)&C[(size_t)gr * DOUT + tx * 2] = make_float2(o[0], o[1]);
        }
    }
}

extern "C" void kernel_launch(void* const* d_in, const int* in_sizes, int n_in,
                              void* d_out, int out_size, void* d_ws, size_t ws_size,
                              hipStream_t stream) {
    const float* x     = (const float*)d_in[0];
    const int*   ei    = (const int*)  d_in[1];
    const float* W1a_l = (const float*)d_in[2];
    const float* b1a   = (const float*)d_in[3];
    const float* W1a_r = (const float*)d_in[4];
    const float* W1b_l = (const float*)d_in[5];
    const float* b1b   = (const float*)d_in[6];
    const float* W1b_r = (const float*)d_in[7];
    const float* W2a_l = (const float*)d_in[8];
    const float* b2a   = (const float*)d_in[9];
    const float* W2a_r = (const float*)d_in[10];
    const float* W2b_l = (const float*)d_in[11];
    const float* b2b   = (const float*)d_in[12];
    const float* W2b_r = (const float*)d_in[13];
    const float* Wlin  = (const float*)d_in[14];
    const float* blin  = (const float*)d_in[15];

    const int N = in_sizes[0] / 128;
    const int E = in_sizes[1] / 2;
    const int* src = ei;
    const int* dst = ei + E;

    size_t o = 0;
    auto take = [&](size_t bytes) -> void* {
        void* p = (char*)d_ws + o;
        o += (bytes + 255) & ~(size_t)255;
        return p;
    };
    int*   cnt     = (int*)  take((size_t)N * 4);
    int*   row_ptr = (int*)  take((size_t)(N + 1) * 4);
    int*   cursor  = (int*)  take((size_t)N * 4);
    float* inv     = (float*)take((size_t)N * 4);
    int*   adj     = (int*)  take((size_t)E * 4);
    float* t       = (float*)take((size_t)N * 64 * 4);
    float* s       = (float*)take((size_t)N * 64 * 4);
    float* hA      = (float*)take((size_t)N * 64 * 4);
    float* hB      = (float*)take((size_t)N * 64 * 4);
    (void)ws_size; (void)n_in; (void)out_size;

    const int mb = (N + 63) / 64;                 // mm blocks
    const int gb = (N * 64 + 255) / 256;          // gather blocks (wave per node)
    const int eb = (E + 255) / 256;

    // ---- build CSR (graph-only, once per call) ----
    hipMemsetAsync(cnt, 0, (size_t)N * 4, stream);
    count_kernel<<<eb, 256, 0, stream>>>(dst, cnt, E);
    inv_kernel<<<(N + 255) / 256, 256, 0, stream>>>(cnt, inv, N);
    scan_kernel<<<1, 1024, 0, stream>>>(cnt, row_ptr, cursor, N);
    fill_kernel<<<eb, 256, 0, stream>>>(src, dst, cursor, adj, E);

    // ---- layer 1a: x[*,128] -> hA[*,64], relu ----
    mm_kernel<128, 64, false, false, false><<<mb, 256, 0, stream>>>(x, W1a_l, nullptr, nullptr, t, N);
    gather_kernel<<<gb, 256, 0, stream>>>(t, adj, row_ptr, inv, s, N);
    mm_kernel<128, 64, true, true, true><<<mb, 256, 0, stream>>>(x, W1a_r, s, b1a, hA, N);

    // ---- layer 1b: hA -> hB, relu ----
    mm_kernel<64, 64, false, false, false><<<mb, 256, 0, stream>>>(hA, W1b_l, nullptr, nullptr, t, N);
    gather_kernel<<<gb, 256, 0, stream>>>(t, adj, row_ptr, inv, s, N);
    mm_kernel<64, 64, true, true, true><<<mb, 256, 0, stream>>>(hA, W1b_r, s, b1b, hB, N);

    // ---- layer 2a: hB -> hA, relu ----
    mm_kernel<64, 64, false, false, false><<<mb, 256, 0, stream>>>(hB, W2a_l, nullptr, nullptr, t, N);
    gather_kernel<<<gb, 256, 0, stream>>>(t, adj, row_ptr, inv, s, N);
    mm_kernel<64, 64, true, true, true><<<mb, 256, 0, stream>>>(hB, W2a_r, s, b2a, hA, N);

    // ---- layer 2b: hA -> hB, NO relu ----
    mm_kernel<64, 64, false, false, false><<<mb, 256, 0, stream>>>(hA, W2b_l, nullptr, nullptr, t, N);
    gather_kernel<<<gb, 256, 0, stream>>>(t, adj, row_ptr, inv, s, N);
    mm_kernel<64, 64, true, true, false><<<mb, 256, 0, stream>>>(hA, W2b_r, s, b2b, hB, N);

    // ---- final linear: hB[*,64] -> out[*,32] ----
    mm_kernel<64, 32, false, true, false><<<mb, 256, 0, stream>>>(hB, Wlin, nullptr, blin, (float*)d_out, N);
}